// Round 1
// baseline (395.460 us; speedup 1.0000x reference)
//
#include <hip/hip_runtime.h>

// ---------------------------------------------------------------------------
// Fused 2-layer LSTM, N=8192, T=28, I=28, H=128, + final [128->10] linear.
// One block = 32 samples through all 28 timesteps of both layers.
// grid = 256 blocks x 512 threads (8 waves) -> exactly 1 block / CU.
//
// R1 restructure (vs 279.6us baseline): ONE barrier per timestep.
//  - h0 and h1 are double-buffered in LDS, which makes a single
//    __syncthreads() per timestep provably race-free:
//      act0 writes h0[t&1]   (prev readers of that buffer finished before
//                             the PREVIOUS barrier -> no pre-write barrier)
//      B_mid                 (h0_t visible; drains x prefetch vmcnt)
//      L1 reads h0[t&1], h1[(t-1)&1]; act1 writes h1[t&1]
//      (visibility of h1_t handled by B_mid of t+1)
//  - x no longer goes through LDS: each wave loads its own A-frag words
//    directly from global (fp32), issued at loop TOP for t+1 (a full phase of
//    latency cover), converted to bf16 frags right after the barrier.
// LDS: wih1 131072 + h0 2x8192 + h1 2x8192 = 163840 B (gfx950 max), dynamic.
// ---------------------------------------------------------------------------

typedef short  short8   __attribute__((ext_vector_type(8)));
typedef float  float4_t __attribute__((ext_vector_type(4)));

#define WIH1_OFF 0        // 131072 B : w_ih1, persistent in LDS
#define H0_OFF   131072   // 2 x 8192 B : h0 double buffer
#define H1_OFF   147456   // 2 x 8192 B : h1 double buffer
#define SMEM_SZ  163840   // full 160 KiB LDS (dynamic alloc)

__device__ __forceinline__ unsigned short bf16r(float v) {
  union { float f; unsigned u; } x; x.f = v;
  unsigned r = x.u + 0x7fffu + ((x.u >> 16) & 1u);   // round-to-nearest-even
  return (unsigned short)(r >> 16);
}
__device__ __forceinline__ float bf2f(unsigned short b) {
  union { unsigned u; float f; } x; x.u = ((unsigned)b) << 16;
  return x.f;
}
__device__ __forceinline__ float sigf(float x)  { return 1.0f / (1.0f + __expf(-x)); }
__device__ __forceinline__ float tanhfast(float x) { return 1.0f - 2.0f / (__expf(2.0f * x) + 1.0f); }

// ---------------------------------------------------------------------------
// Prologue: pack weights (fp32 -> bf16) into MFMA B-frag tiled layout in ws.
// ws (unsigned short units):
//   [0      ,16384) : w_ih0  [1 kc][32 tiles][64 lanes][8]  (k padded to 32)
//   [16384  ,81920) : w_hh0  [4 kc][32 tiles][64][8]
//   [81920 ,147456) : w_ih1  [4 kc][32][64][8]
//   [147456,212992) : w_hh1  [4 kc][32][64][8]
// element (tile,lane,j): row = tile*16 + (lane&15), k = kc*32 + (lane>>4)*8 + j
// ---------------------------------------------------------------------------
__global__ void pack_weights(const float* __restrict__ wih0, const float* __restrict__ whh0,
                             const float* __restrict__ wih1, const float* __restrict__ whh1,
                             unsigned short* __restrict__ dst)
{
  int e = blockIdx.x * 256 + threadIdx.x;
  const float* src; int K; int i;
  if      (e < 16384)  { src = wih0; K = 28;  i = e;          }
  else if (e < 81920)  { src = whh0; K = 128; i = e - 16384;  }
  else if (e < 147456) { src = wih1; K = 128; i = e - 81920;  }
  else if (e < 212992) { src = whh1; K = 128; i = e - 147456; }
  else return;
  int j = i & 7, lane = (i >> 3) & 63, tile = (i >> 9) & 31, kc = i >> 14;
  int row = tile * 16 + (lane & 15);
  int k = kc * 32 + ((lane >> 4) << 3) + j;
  float v = (k < K) ? src[row * K + k] : 0.0f;
  dst[e] = bf16r(v);
}

// ---------------------------------------------------------------------------
// Main fused kernel.
// ---------------------------------------------------------------------------
__global__ __launch_bounds__(512, 2)
void lstm_fused(const float* __restrict__ xg,
                const unsigned short* __restrict__ wpack,
                const float* __restrict__ bih0, const float* __restrict__ bhh0,
                const float* __restrict__ bih1, const float* __restrict__ bhh1,
                const float* __restrict__ wout, const float* __restrict__ bout,
                float* __restrict__ out)
{
  extern __shared__ __align__(16) char smem[];

  const int tid  = threadIdx.x;
  const int lane = tid & 63;
  const int wave = tid >> 6;          // 0..7, owns h-dims [wave*16, wave*16+16)
  const int q    = lane >> 4;         // quad: acc rows q*4 .. q*4+3
  const int mcol = lane & 15;         // acc col = h-dim within wave slice
  const int n0   = blockIdx.x * 32;   // batch tile base

  const short8* wp = (const short8*)wpack;

  // ---- persistent weight fragments in registers --------------------------
  short8 wih0[4], whh0[4][4], whh1[4][4];          // [g] / [kc][g]
#pragma unroll
  for (int g = 0; g < 4; ++g)
    wih0[g] = wp[(g * 8 + wave) * 64 + lane];
#pragma unroll
  for (int kc = 0; kc < 4; ++kc)
#pragma unroll
    for (int g = 0; g < 4; ++g) {
      whh0[kc][g] = wp[ 2048 + (kc * 32 + g * 8 + wave) * 64 + lane];
      whh1[kc][g] = wp[18432 + (kc * 32 + g * 8 + wave) * 64 + lane];
    }

  // ---- persistent w_ih1 in LDS (131072 B) --------------------------------
  {
    short8* dstp = (short8*)smem;
#pragma unroll
    for (int rr = 0; rr < 16; ++rr)
      dstp[rr * 512 + tid] = wp[10240 + rr * 512 + tid];
  }

  // ---- biases (per-lane, gate g, dim = wave*16+mcol) ---------------------
  float bias0[4], bias1[4];
  {
    const int d = wave * 16 + mcol;
#pragma unroll
    for (int g = 0; g < 4; ++g) {
      bias0[g] = bih0[g * 128 + d] + bhh0[g * 128 + d];
      bias1[g] = bih1[g * 128 + d] + bhh1[g * 128 + d];
    }
  }

  // ---- zero the "B" halves of h0/h1 (read as h_{-1} at t=0) --------------
  {
    int* z0 = (int*)(smem + H0_OFF + 8192);
    int* z1 = (int*)(smem + H1_OFF + 8192);
#pragma unroll
    for (int rr = 0; rr < 4; ++rr) { z0[rr * 512 + tid] = 0; z1[rr * 512 + tid] = 0; }
  }

  // ---- x prefetch: per-wave direct global fp32 loads (no LDS) ------------
  // lane needs x[n0 + mt*16 + (lane&15)][t*28 + q*8 + j], j=0..7 (k pad->0).
  float4_t xa[2], xb[2];   // pending fp32 for t+1
  short8   xf[2];          // current bf16 A-frags
  auto issue_x = [&](int t) {
#pragma unroll
    for (int mt = 0; mt < 2; ++mt) {
      const float* xsrc = xg + (size_t)(n0 + mt * 16 + mcol) * 784 + t * 28 + q * 8;
      xa[mt] = *(const float4_t*)xsrc;
      // q==3: only k=24..27 valid; clamp addr (stay in-bounds), zero after.
      const float* x2 = xsrc + ((q == 3) ? 0 : 4);
      float4_t v = *(const float4_t*)x2;
      if (q == 3) v = (float4_t){0.f, 0.f, 0.f, 0.f};
      xb[mt] = v;
    }
  };
  auto cvt_x = [&]() {
#pragma unroll
    for (int mt = 0; mt < 2; ++mt) {
      short8 f;
#pragma unroll
      for (int j = 0; j < 4; ++j) {
        f[j]     = (short)bf16r(xa[mt][j]);
        f[j + 4] = (short)bf16r(xb[mt][j]);
      }
      xf[mt] = f;
    }
  };

  issue_x(0);
  __syncthreads();   // wih1 + h-zeros visible; x_0 loads drained
  cvt_x();

  // per-lane constant part of the h-write address (A-frag tiled position of
  // element (s, d) with d = wave*16+mcol):
  const int kc_d   = wave >> 1;
  const int sub    = ((wave & 1) << 1) | (mcol >> 3);
  const int hconst = kc_d * 1024 + sub * 256 + q * 64 + (mcol & 7) * 2;

  int h0r = H0_OFF + 8192, h0w = H0_OFF;   // t=0: read zeros (B), write A
  int h1r = H1_OFF + 8192, h1w = H1_OFF;

  float c0[2][4] = {{0.f,0.f,0.f,0.f},{0.f,0.f,0.f,0.f}};
  float c1[2][4] = {{0.f,0.f,0.f,0.f},{0.f,0.f,0.f,0.f}};

  const short8* W1f = (const short8*)(smem + WIH1_OFF);

#pragma unroll 1
  for (int t = 0; t < 28; ++t) {
    float4_t acc[2][4];
    unsigned short hb[2][4];

    // issue x_{t+1} loads NOW: a full L0 phase of latency cover; the single
    // barrier's vmcnt(0) drain lands them for free.
    if (t < 27) issue_x(t + 1);

    // ================= LAYER 0 : gates = b0 + x_t@Wih0^T + h0@Whh0^T =====
#pragma unroll
    for (int mt = 0; mt < 2; ++mt)
#pragma unroll
      for (int g = 0; g < 4; ++g)
        acc[mt][g] = (float4_t){bias0[g], bias0[g], bias0[g], bias0[g]};
#pragma unroll
    for (int mt = 0; mt < 2; ++mt)
#pragma unroll
      for (int g = 0; g < 4; ++g)
        acc[mt][g] = __builtin_amdgcn_mfma_f32_16x16x32_bf16(xf[mt], wih0[g], acc[mt][g], 0, 0, 0);
    {
      const short8* H0R = (const short8*)(smem + h0r);
#pragma unroll
      for (int kc = 0; kc < 4; ++kc)
#pragma unroll
        for (int mt = 0; mt < 2; ++mt) {
          short8 hf = H0R[(mt * 4 + kc) * 64 + lane];
#pragma unroll
          for (int g = 0; g < 4; ++g)
            acc[mt][g] = __builtin_amdgcn_mfma_f32_16x16x32_bf16(hf, whh0[kc][g], acc[mt][g], 0, 0, 0);
        }
    }
    // activations (gate order i,f,g,o); c stays in registers
#pragma unroll
    for (int mt = 0; mt < 2; ++mt)
#pragma unroll
      for (int r = 0; r < 4; ++r) {
        float c = sigf(acc[mt][1][r]) * c0[mt][r] + sigf(acc[mt][0][r]) * tanhfast(acc[mt][2][r]);
        c0[mt][r] = c;
        hb[mt][r] = bf16r(sigf(acc[mt][3][r]) * tanhfast(c));
      }
    // write h0_t into the OTHER buffer: its previous readers (L1(t-2) and
    // L0(t-1)) all finished before the previous barrier -> no pre-barrier.
#pragma unroll
    for (int mt = 0; mt < 2; ++mt)
#pragma unroll
      for (int r = 0; r < 4; ++r)
        *(unsigned short*)(smem + h0w + mt * 4096 + r * 16 + hconst) = hb[mt][r];

    __syncthreads();   // THE barrier: h0_t visible; x_{t+1} loads drained

    if (t < 27) cvt_x();  // fp32 -> bf16 frags for next iteration

    // ================= LAYER 1 : gates = b1 + h0_t@Wih1^T + h1@Whh1^T ====
#pragma unroll
    for (int mt = 0; mt < 2; ++mt)
#pragma unroll
      for (int g = 0; g < 4; ++g)
        acc[mt][g] = (float4_t){bias1[g], bias1[g], bias1[g], bias1[g]};
    {
      const short8* H0W = (const short8*)(smem + h0w);
#pragma unroll
      for (int kc = 0; kc < 4; ++kc) {
        short8 wf[4];
#pragma unroll
        for (int g = 0; g < 4; ++g)
          wf[g] = W1f[(kc * 32 + g * 8 + wave) * 64 + lane];
#pragma unroll
        for (int mt = 0; mt < 2; ++mt) {
          short8 hf = H0W[(mt * 4 + kc) * 64 + lane];
#pragma unroll
          for (int g = 0; g < 4; ++g)
            acc[mt][g] = __builtin_amdgcn_mfma_f32_16x16x32_bf16(hf, wf[g], acc[mt][g], 0, 0, 0);
        }
      }
      const short8* H1R = (const short8*)(smem + h1r);
#pragma unroll
      for (int kc = 0; kc < 4; ++kc)
#pragma unroll
        for (int mt = 0; mt < 2; ++mt) {
          short8 hf = H1R[(mt * 4 + kc) * 64 + lane];
#pragma unroll
          for (int g = 0; g < 4; ++g)
            acc[mt][g] = __builtin_amdgcn_mfma_f32_16x16x32_bf16(hf, whh1[kc][g], acc[mt][g], 0, 0, 0);
        }
    }
    // activations
#pragma unroll
    for (int mt = 0; mt < 2; ++mt)
#pragma unroll
      for (int r = 0; r < 4; ++r) {
        float c = sigf(acc[mt][1][r]) * c1[mt][r] + sigf(acc[mt][0][r]) * tanhfast(acc[mt][2][r]);
        c1[mt][r] = c;
        hb[mt][r] = bf16r(sigf(acc[mt][3][r]) * tanhfast(c));
      }
    // write h1_t (other buffer; prev readers done before THIS t's barrier;
    // visibility for L1(t+1) is provided by the NEXT t's barrier)
#pragma unroll
    for (int mt = 0; mt < 2; ++mt)
#pragma unroll
      for (int r = 0; r < 4; ++r)
        *(unsigned short*)(smem + h1w + mt * 4096 + r * 16 + hconst) = hb[mt][r];

    h0r ^= 8192; h0w ^= 8192; h1r ^= 8192; h1w ^= 8192;
  }
  __syncthreads();     // final h1 (buffer B: t=27 wrote H1_OFF+8192) visible

  // ================= epilogue: out[s][o] = h1 . wout[o] + bout[o] =========
  if (tid < 320) {
    const short8* H1f = (const short8*)(smem + H1_OFF + 8192);
    int s = tid / 10, o = tid - (tid / 10) * 10;
    float sum = bout[o];
#pragma unroll
    for (int kc = 0; kc < 4; ++kc)
#pragma unroll
      for (int sb = 0; sb < 4; ++sb) {
        short8 hv = H1f[((s >> 4) * 4 + kc) * 64 + sb * 16 + (s & 15)];
        int dbase = kc * 32 + sb * 8;
        float4_t w0 = *(const float4_t*)(wout + o * 128 + dbase);
        float4_t w1 = *(const float4_t*)(wout + o * 128 + dbase + 4);
#pragma unroll
        for (int j = 0; j < 4; ++j) {
          sum += bf2f((unsigned short)hv[j])     * w0[j];
          sum += bf2f((unsigned short)hv[j + 4]) * w1[j];
        }
      }
    out[(size_t)(n0 + s) * 10 + o] = sum;
  }
}

extern "C" void kernel_launch(void* const* d_in, const int* in_sizes, int n_in,
                              void* d_out, int out_size, void* d_ws, size_t ws_size,
                              hipStream_t stream) {
  const float* x    = (const float*)d_in[0];
  const float* wih0 = (const float*)d_in[1];
  const float* whh0 = (const float*)d_in[2];
  const float* bih0 = (const float*)d_in[3];
  const float* bhh0 = (const float*)d_in[4];
  const float* wih1 = (const float*)d_in[5];
  const float* whh1 = (const float*)d_in[6];
  const float* bih1 = (const float*)d_in[7];
  const float* bhh1 = (const float*)d_in[8];
  const float* wout = (const float*)d_in[9];
  const float* bout = (const float*)d_in[10];

  unsigned short* wp = (unsigned short*)d_ws;   // 425984 B used

  pack_weights<<<832, 256, 0, stream>>>(wih0, whh0, wih1, whh1, wp);
  lstm_fused<<<256, 512, SMEM_SZ, stream>>>(x, wp, bih0, bhh0, bih1, bhh1, wout, bout,
                                            (float*)d_out);
}

// Round 2
// 390.275 us; speedup vs baseline: 1.0133x; 1.0133x over previous
//
#include <hip/hip_runtime.h>

// ---------------------------------------------------------------------------
// Fused 2-layer LSTM, N=8192, T=28, I=28, H=128, + final [128->10] linear.
// One block = 32 samples through all 28 timesteps of both layers.
// grid = 256 blocks x 512 threads (8 waves) -> exactly 1 block / CU.
//
// R2: __launch_bounds__(512, 1).  R1's (512,2) capped VGPRs at 128 while the
// persistent weight fragments alone need 144 -> everything spilled to scratch
// (rocprof: WRITE_SIZE 398 MB vs 0.33 MB of real output writes).  One block
// per CU is all the grid can use anyway (256 blocks / 256 CUs), so cap at
// 2 waves/SIMD and let the allocator keep the ~240-VGPR working set resident.
//
// Structure (from R1): ONE barrier per timestep.
//  - h0 and h1 double-buffered in LDS:
//      act0 writes h0[t&1]   (prev readers finished before PREVIOUS barrier)
//      B_mid                 (h0_t visible; drains x prefetch vmcnt)
//      L1 reads h0[t&1], h1[(t-1)&1]; act1 writes h1[t&1]
//      (h1_t visibility handled by B_mid of t+1)
//  - x loaded per-wave directly from global (fp32) at loop TOP for t+1,
//    converted to bf16 frags right after the barrier.
// LDS: wih1 131072 + h0 2x8192 + h1 2x8192 = 163840 B (gfx950 max), dynamic.
// ---------------------------------------------------------------------------

typedef short  short8   __attribute__((ext_vector_type(8)));
typedef float  float4_t __attribute__((ext_vector_type(4)));

#define WIH1_OFF 0        // 131072 B : w_ih1, persistent in LDS
#define H0_OFF   131072   // 2 x 8192 B : h0 double buffer
#define H1_OFF   147456   // 2 x 8192 B : h1 double buffer
#define SMEM_SZ  163840   // full 160 KiB LDS (dynamic alloc)

__device__ __forceinline__ unsigned short bf16r(float v) {
  union { float f; unsigned u; } x; x.f = v;
  unsigned r = x.u + 0x7fffu + ((x.u >> 16) & 1u);   // round-to-nearest-even
  return (unsigned short)(r >> 16);
}
__device__ __forceinline__ float bf2f(unsigned short b) {
  union { unsigned u; float f; } x; x.u = ((unsigned)b) << 16;
  return x.f;
}
__device__ __forceinline__ float sigf(float x)  { return 1.0f / (1.0f + __expf(-x)); }
__device__ __forceinline__ float tanhfast(float x) { return 1.0f - 2.0f / (__expf(2.0f * x) + 1.0f); }

// ---------------------------------------------------------------------------
// Prologue: pack weights (fp32 -> bf16) into MFMA B-frag tiled layout in ws.
// ws (unsigned short units):
//   [0      ,16384) : w_ih0  [1 kc][32 tiles][64 lanes][8]  (k padded to 32)
//   [16384  ,81920) : w_hh0  [4 kc][32 tiles][64][8]
//   [81920 ,147456) : w_ih1  [4 kc][32][64][8]
//   [147456,212992) : w_hh1  [4 kc][32][64][8]
// element (tile,lane,j): row = tile*16 + (lane&15), k = kc*32 + (lane>>4)*8 + j
// ---------------------------------------------------------------------------
__global__ void pack_weights(const float* __restrict__ wih0, const float* __restrict__ whh0,
                             const float* __restrict__ wih1, const float* __restrict__ whh1,
                             unsigned short* __restrict__ dst)
{
  int e = blockIdx.x * 256 + threadIdx.x;
  const float* src; int K; int i;
  if      (e < 16384)  { src = wih0; K = 28;  i = e;          }
  else if (e < 81920)  { src = whh0; K = 128; i = e - 16384;  }
  else if (e < 147456) { src = wih1; K = 128; i = e - 81920;  }
  else if (e < 212992) { src = whh1; K = 128; i = e - 147456; }
  else return;
  int j = i & 7, lane = (i >> 3) & 63, tile = (i >> 9) & 31, kc = i >> 14;
  int row = tile * 16 + (lane & 15);
  int k = kc * 32 + ((lane >> 4) << 3) + j;
  float v = (k < K) ? src[row * K + k] : 0.0f;
  dst[e] = bf16r(v);
}

// ---------------------------------------------------------------------------
// Main fused kernel.
// ---------------------------------------------------------------------------
__global__ __launch_bounds__(512, 1)
void lstm_fused(const float* __restrict__ xg,
                const unsigned short* __restrict__ wpack,
                const float* __restrict__ bih0, const float* __restrict__ bhh0,
                const float* __restrict__ bih1, const float* __restrict__ bhh1,
                const float* __restrict__ wout, const float* __restrict__ bout,
                float* __restrict__ out)
{
  extern __shared__ __align__(16) char smem[];

  const int tid  = threadIdx.x;
  const int lane = tid & 63;
  const int wave = tid >> 6;          // 0..7, owns h-dims [wave*16, wave*16+16)
  const int q    = lane >> 4;         // quad: acc rows q*4 .. q*4+3
  const int mcol = lane & 15;         // acc col = h-dim within wave slice
  const int n0   = blockIdx.x * 32;   // batch tile base

  const short8* wp = (const short8*)wpack;

  // ---- persistent weight fragments in registers --------------------------
  short8 wih0[4], whh0[4][4], whh1[4][4];          // [g] / [kc][g]
#pragma unroll
  for (int g = 0; g < 4; ++g)
    wih0[g] = wp[(g * 8 + wave) * 64 + lane];
#pragma unroll
  for (int kc = 0; kc < 4; ++kc)
#pragma unroll
    for (int g = 0; g < 4; ++g) {
      whh0[kc][g] = wp[ 2048 + (kc * 32 + g * 8 + wave) * 64 + lane];
      whh1[kc][g] = wp[18432 + (kc * 32 + g * 8 + wave) * 64 + lane];
    }

  // ---- persistent w_ih1 in LDS (131072 B) --------------------------------
  {
    short8* dstp = (short8*)smem;
#pragma unroll
    for (int rr = 0; rr < 16; ++rr)
      dstp[rr * 512 + tid] = wp[10240 + rr * 512 + tid];
  }

  // ---- biases (per-lane, gate g, dim = wave*16+mcol) ---------------------
  float bias0[4], bias1[4];
  {
    const int d = wave * 16 + mcol;
#pragma unroll
    for (int g = 0; g < 4; ++g) {
      bias0[g] = bih0[g * 128 + d] + bhh0[g * 128 + d];
      bias1[g] = bih1[g * 128 + d] + bhh1[g * 128 + d];
    }
  }

  // ---- zero the "B" halves of h0/h1 (read as h_{-1} at t=0) --------------
  {
    int* z0 = (int*)(smem + H0_OFF + 8192);
    int* z1 = (int*)(smem + H1_OFF + 8192);
#pragma unroll
    for (int rr = 0; rr < 4; ++rr) { z0[rr * 512 + tid] = 0; z1[rr * 512 + tid] = 0; }
  }

  // ---- x prefetch: per-wave direct global fp32 loads (no LDS) ------------
  // lane needs x[n0 + mt*16 + (lane&15)][t*28 + q*8 + j], j=0..7 (k pad->0).
  float4_t xa[2], xb[2];   // pending fp32 for t+1
  short8   xf[2];          // current bf16 A-frags
  auto issue_x = [&](int t) {
#pragma unroll
    for (int mt = 0; mt < 2; ++mt) {
      const float* xsrc = xg + (size_t)(n0 + mt * 16 + mcol) * 784 + t * 28 + q * 8;
      xa[mt] = *(const float4_t*)xsrc;
      // q==3: only k=24..27 valid; clamp addr (stay in-bounds), zero after.
      const float* x2 = xsrc + ((q == 3) ? 0 : 4);
      float4_t v = *(const float4_t*)x2;
      if (q == 3) v = (float4_t){0.f, 0.f, 0.f, 0.f};
      xb[mt] = v;
    }
  };
  auto cvt_x = [&]() {
#pragma unroll
    for (int mt = 0; mt < 2; ++mt) {
      short8 f;
#pragma unroll
      for (int j = 0; j < 4; ++j) {
        f[j]     = (short)bf16r(xa[mt][j]);
        f[j + 4] = (short)bf16r(xb[mt][j]);
      }
      xf[mt] = f;
    }
  };

  issue_x(0);
  __syncthreads();   // wih1 + h-zeros visible; x_0 loads drained
  cvt_x();

  // per-lane constant part of the h-write address (A-frag tiled position of
  // element (s, d) with d = wave*16+mcol):
  const int kc_d   = wave >> 1;
  const int sub    = ((wave & 1) << 1) | (mcol >> 3);
  const int hconst = kc_d * 1024 + sub * 256 + q * 64 + (mcol & 7) * 2;

  int h0r = H0_OFF + 8192, h0w = H0_OFF;   // t=0: read zeros (B), write A
  int h1r = H1_OFF + 8192, h1w = H1_OFF;

  float c0[2][4] = {{0.f,0.f,0.f,0.f},{0.f,0.f,0.f,0.f}};
  float c1[2][4] = {{0.f,0.f,0.f,0.f},{0.f,0.f,0.f,0.f}};

  const short8* W1f = (const short8*)(smem + WIH1_OFF);

#pragma unroll 1
  for (int t = 0; t < 28; ++t) {
    float4_t acc[2][4];
    unsigned short hb[2][4];

    // issue x_{t+1} loads NOW: a full L0 phase of latency cover; the single
    // barrier's vmcnt(0) drain lands them for free.
    if (t < 27) issue_x(t + 1);

    // ================= LAYER 0 : gates = b0 + x_t@Wih0^T + h0@Whh0^T =====
#pragma unroll
    for (int mt = 0; mt < 2; ++mt)
#pragma unroll
      for (int g = 0; g < 4; ++g)
        acc[mt][g] = (float4_t){bias0[g], bias0[g], bias0[g], bias0[g]};
#pragma unroll
    for (int mt = 0; mt < 2; ++mt)
#pragma unroll
      for (int g = 0; g < 4; ++g)
        acc[mt][g] = __builtin_amdgcn_mfma_f32_16x16x32_bf16(xf[mt], wih0[g], acc[mt][g], 0, 0, 0);
    {
      const short8* H0R = (const short8*)(smem + h0r);
#pragma unroll
      for (int kc = 0; kc < 4; ++kc)
#pragma unroll
        for (int mt = 0; mt < 2; ++mt) {
          short8 hf = H0R[(mt * 4 + kc) * 64 + lane];
#pragma unroll
          for (int g = 0; g < 4; ++g)
            acc[mt][g] = __builtin_amdgcn_mfma_f32_16x16x32_bf16(hf, whh0[kc][g], acc[mt][g], 0, 0, 0);
        }
    }
    // activations (gate order i,f,g,o); c stays in registers
#pragma unroll
    for (int mt = 0; mt < 2; ++mt)
#pragma unroll
      for (int r = 0; r < 4; ++r) {
        float c = sigf(acc[mt][1][r]) * c0[mt][r] + sigf(acc[mt][0][r]) * tanhfast(acc[mt][2][r]);
        c0[mt][r] = c;
        hb[mt][r] = bf16r(sigf(acc[mt][3][r]) * tanhfast(c));
      }
    // write h0_t into the OTHER buffer: its previous readers (L1(t-2) and
    // L0(t-1)) all finished before the previous barrier -> no pre-barrier.
#pragma unroll
    for (int mt = 0; mt < 2; ++mt)
#pragma unroll
      for (int r = 0; r < 4; ++r)
        *(unsigned short*)(smem + h0w + mt * 4096 + r * 16 + hconst) = hb[mt][r];

    __syncthreads();   // THE barrier: h0_t visible; x_{t+1} loads drained

    if (t < 27) cvt_x();  // fp32 -> bf16 frags for next iteration

    // ================= LAYER 1 : gates = b1 + h0_t@Wih1^T + h1@Whh1^T ====
#pragma unroll
    for (int mt = 0; mt < 2; ++mt)
#pragma unroll
      for (int g = 0; g < 4; ++g)
        acc[mt][g] = (float4_t){bias1[g], bias1[g], bias1[g], bias1[g]};
    {
      const short8* H0W = (const short8*)(smem + h0w);
#pragma unroll
      for (int kc = 0; kc < 4; ++kc) {
        short8 wf[4];
#pragma unroll
        for (int g = 0; g < 4; ++g)
          wf[g] = W1f[(kc * 32 + g * 8 + wave) * 64 + lane];
#pragma unroll
        for (int mt = 0; mt < 2; ++mt) {
          short8 hf = H0W[(mt * 4 + kc) * 64 + lane];
#pragma unroll
          for (int g = 0; g < 4; ++g)
            acc[mt][g] = __builtin_amdgcn_mfma_f32_16x16x32_bf16(hf, wf[g], acc[mt][g], 0, 0, 0);
        }
      }
      const short8* H1R = (const short8*)(smem + h1r);
#pragma unroll
      for (int kc = 0; kc < 4; ++kc)
#pragma unroll
        for (int mt = 0; mt < 2; ++mt) {
          short8 hf = H1R[(mt * 4 + kc) * 64 + lane];
#pragma unroll
          for (int g = 0; g < 4; ++g)
            acc[mt][g] = __builtin_amdgcn_mfma_f32_16x16x32_bf16(hf, whh1[kc][g], acc[mt][g], 0, 0, 0);
        }
    }
    // activations
#pragma unroll
    for (int mt = 0; mt < 2; ++mt)
#pragma unroll
      for (int r = 0; r < 4; ++r) {
        float c = sigf(acc[mt][1][r]) * c1[mt][r] + sigf(acc[mt][0][r]) * tanhfast(acc[mt][2][r]);
        c1[mt][r] = c;
        hb[mt][r] = bf16r(sigf(acc[mt][3][r]) * tanhfast(c));
      }
    // write h1_t (other buffer; prev readers done before THIS t's barrier;
    // visibility for L1(t+1) is provided by the NEXT t's barrier)
#pragma unroll
    for (int mt = 0; mt < 2; ++mt)
#pragma unroll
      for (int r = 0; r < 4; ++r)
        *(unsigned short*)(smem + h1w + mt * 4096 + r * 16 + hconst) = hb[mt][r];

    h0r ^= 8192; h0w ^= 8192; h1r ^= 8192; h1w ^= 8192;
  }
  __syncthreads();     // final h1 (buffer B: t=27 wrote H1_OFF+8192) visible

  // ================= epilogue: out[s][o] = h1 . wout[o] + bout[o] =========
  if (tid < 320) {
    const short8* H1f = (const short8*)(smem + H1_OFF + 8192);
    int s = tid / 10, o = tid - (tid / 10) * 10;
    float sum = bout[o];
#pragma unroll
    for (int kc = 0; kc < 4; ++kc)
#pragma unroll
      for (int sb = 0; sb < 4; ++sb) {
        short8 hv = H1f[((s >> 4) * 4 + kc) * 64 + sb * 16 + (s & 15)];
        int dbase = kc * 32 + sb * 8;
        float4_t w0 = *(const float4_t*)(wout + o * 128 + dbase);
        float4_t w1 = *(const float4_t*)(wout + o * 128 + dbase + 4);
#pragma unroll
        for (int j = 0; j < 4; ++j) {
          sum += bf2f((unsigned short)hv[j])     * w0[j];
          sum += bf2f((unsigned short)hv[j + 4]) * w1[j];
        }
      }
    out[(size_t)(n0 + s) * 10 + o] = sum;
  }
}

extern "C" void kernel_launch(void* const* d_in, const int* in_sizes, int n_in,
                              void* d_out, int out_size, void* d_ws, size_t ws_size,
                              hipStream_t stream) {
  const float* x    = (const float*)d_in[0];
  const float* wih0 = (const float*)d_in[1];
  const float* whh0 = (const float*)d_in[2];
  const float* bih0 = (const float*)d_in[3];
  const float* bhh0 = (const float*)d_in[4];
  const float* wih1 = (const float*)d_in[5];
  const float* whh1 = (const float*)d_in[6];
  const float* bih1 = (const float*)d_in[7];
  const float* bhh1 = (const float*)d_in[8];
  const float* wout = (const float*)d_in[9];
  const float* bout = (const float*)d_in[10];

  unsigned short* wp = (unsigned short*)d_ws;   // 425984 B used

  pack_weights<<<832, 256, 0, stream>>>(wih0, whh0, wih1, whh1, wp);
  lstm_fused<<<256, 512, SMEM_SZ, stream>>>(x, wp, bih0, bhh0, bih1, bhh1, wout, bout,
                                            (float*)d_out);
}

// Round 6
// 282.383 us; speedup vs baseline: 1.4004x; 1.3821x over previous
//
#include <hip/hip_runtime.h>

// ---------------------------------------------------------------------------
// Fused 2-layer LSTM, N=8192, T=28, I=28, H=128, + final [128->10] linear.
// One block = 32 samples through all 28 timesteps of both layers.
// grid = 256 blocks x 512 threads (8 waves) -> exactly 1 block / CU.
//
// R6: the verified 279.6us baseline structure with ONE barrier removed per
// timestep.  Evidence trail:
//   - R1/R2 (x prefetched in registers): +24 persistent VGPRs pushed the
//     ~250-reg working set over the 256/wave cap (2 waves/SIMD, 512-reg
//     SIMD file) -> ~27 regs spilled to scratch every iteration
//     (WRITE_SIZE ~398 MB vs 0.33 MB real output) -> 358-390us.
//   - R3-R5 (asm MFMA w/ AGPR-pinned weights): numerically unstable
//     (NaN / 3.4e-3) -- inline-asm MFMA hazards unresolvable blind. Dropped.
//   - R6: x goes back through LDS (transient regs only, baseline-proven);
//     all MFMAs are builtins; registers identical to the 279.6 baseline.
// Barrier reduction: h0 is double-buffered (+8KB LDS), so L0's h0_t write
// needs no pre-barrier:
//   buf[t&1] previously held h0_{t-2}; its readers were L1(t-2) (before
//   BarB(t-2)) and L0(t-1) (before BarA(t-1)) -- all complete before
//   BarB(t-1), which precedes this write.  Schedule per t:
//     L0: read x_t + h0_{t-1}[buf (t-1)&1] -> MFMA -> acts -> write
//         h0_t[buf t&1]                                   (no pre-barrier)
//     BarA: h0_t visible
//     L1: read h0_t + h1_{t-1} (single buf) -> MFMA; stage_x(t+1); acts->hb
//     BarB: all h1_{t-1} reads done; x_{t+1} visible for t+1
//     write h1_t (single buf; visible to L1(t+1) via BarA(t+1))
//   3 barriers/t -> 2 (84 -> 56 full-drain points).
// LDS: wih1 131072 + h0 2x8192 + h1 8192 + x 2048 = 157696 <= 163840.
// ---------------------------------------------------------------------------

typedef short  short8   __attribute__((ext_vector_type(8)));
typedef float  float4_t __attribute__((ext_vector_type(4)));

#define WIH1_OFF 0        // 131072 B : w_ih1, persistent in LDS
#define H0_OFF   131072   // 2 x 8192 B : h0 double buffer
#define H1_OFF   147456   //     8192 B : h1 single buffer
#define X_OFF    155648   //     2048 B : x_t tile (k padded 28->32, zeros)
#define SMEM_SZ  157696

__device__ __forceinline__ unsigned short bf16r(float v) {
  union { float f; unsigned u; } x; x.f = v;
  unsigned r = x.u + 0x7fffu + ((x.u >> 16) & 1u);   // round-to-nearest-even
  return (unsigned short)(r >> 16);
}
__device__ __forceinline__ float bf2f(unsigned short b) {
  union { unsigned u; float f; } x; x.u = ((unsigned)b) << 16;
  return x.f;
}
__device__ __forceinline__ float sigf(float x)  { return 1.0f / (1.0f + __expf(-x)); }
__device__ __forceinline__ float tanhfast(float x) { return 1.0f - 2.0f / (__expf(2.0f * x) + 1.0f); }

// ---------------------------------------------------------------------------
// Prologue: pack weights (fp32 -> bf16) into MFMA B-frag tiled layout in ws.
// ws (unsigned short units):
//   [0      ,16384) : w_ih0  [1 kc][32 tiles][64 lanes][8]  (k padded to 32)
//   [16384  ,81920) : w_hh0  [4 kc][32 tiles][64][8]
//   [81920 ,147456) : w_ih1  [4 kc][32][64][8]
//   [147456,212992) : w_hh1  [4 kc][32][64][8]
// element (tile,lane,j): row = tile*16 + (lane&15), k = kc*32 + (lane>>4)*8 + j
// ---------------------------------------------------------------------------
__global__ void pack_weights(const float* __restrict__ wih0, const float* __restrict__ whh0,
                             const float* __restrict__ wih1, const float* __restrict__ whh1,
                             unsigned short* __restrict__ dst)
{
  int e = blockIdx.x * 256 + threadIdx.x;
  const float* src; int K; int i;
  if      (e < 16384)  { src = wih0; K = 28;  i = e;          }
  else if (e < 81920)  { src = whh0; K = 128; i = e - 16384;  }
  else if (e < 147456) { src = wih1; K = 128; i = e - 81920;  }
  else if (e < 212992) { src = whh1; K = 128; i = e - 147456; }
  else return;
  int j = i & 7, lane = (i >> 3) & 63, tile = (i >> 9) & 31, kc = i >> 14;
  int row = tile * 16 + (lane & 15);
  int k = kc * 32 + ((lane >> 4) << 3) + j;
  float v = (k < K) ? src[row * K + k] : 0.0f;
  dst[e] = bf16r(v);
}

// ---------------------------------------------------------------------------
// Main fused kernel.
// ---------------------------------------------------------------------------
__global__ __launch_bounds__(512, 2)
void lstm_fused(const float* __restrict__ xg,
                const unsigned short* __restrict__ wpack,
                const float* __restrict__ bih0, const float* __restrict__ bhh0,
                const float* __restrict__ bih1, const float* __restrict__ bhh1,
                const float* __restrict__ wout, const float* __restrict__ bout,
                float* __restrict__ out)
{
  __shared__ __align__(16) char smem[SMEM_SZ];

  const int tid  = threadIdx.x;
  const int lane = tid & 63;
  const int wave = tid >> 6;          // 0..7, owns h-dims [wave*16, wave*16+16)
  const int q    = lane >> 4;         // quad: acc rows q*4 .. q*4+3
  const int mcol = lane & 15;         // acc col = h-dim within wave slice
  const int n0   = blockIdx.x * 32;   // batch tile base

  const short8* wp = (const short8*)wpack;

  // ---- persistent weight fragments in registers --------------------------
  short8 wih0[4], whh0[4][4], whh1[4][4];          // [g] / [kc][g]
#pragma unroll
  for (int g = 0; g < 4; ++g)
    wih0[g] = wp[(g * 8 + wave) * 64 + lane];
#pragma unroll
  for (int kc = 0; kc < 4; ++kc)
#pragma unroll
    for (int g = 0; g < 4; ++g) {
      whh0[kc][g] = wp[ 2048 + (kc * 32 + g * 8 + wave) * 64 + lane];
      whh1[kc][g] = wp[18432 + (kc * 32 + g * 8 + wave) * 64 + lane];
    }

  // ---- persistent w_ih1 in LDS (131072 B) --------------------------------
  {
    short8* dstp = (short8*)smem;
#pragma unroll
    for (int rr = 0; rr < 16; ++rr)
      dstp[rr * 512 + tid] = wp[10240 + rr * 512 + tid];
  }

  // ---- biases (per-lane, gate g, dim = wave*16+mcol) ---------------------
  float bias0[4], bias1[4];
  {
    const int d = wave * 16 + mcol;
#pragma unroll
    for (int g = 0; g < 4; ++g) {
      bias0[g] = bih0[g * 128 + d] + bhh0[g * 128 + d];
      bias1[g] = bih1[g * 128 + d] + bhh1[g * 128 + d];
    }
  }

  // ---- zero h0 read-buffer (B half), h1, and x pad region ---------------
  {
    int* z0 = (int*)(smem + H0_OFF + 8192);   // h0 buf1 (read as h0_{-1})
    int* z1 = (int*)(smem + H1_OFF);          // h1
#pragma unroll
    for (int rr = 0; rr < 4; ++rr) { z0[rr * 512 + tid] = 0; z1[rr * 512 + tid] = 0; }
    ((int*)(smem + X_OFF))[tid] = 0;          // x tile incl. k=28..31 pad
  }

  // ---- x_t staging: fp32 global -> bf16 A-frag tile in LDS ---------------
  auto stage_x = [&](int t) {
    if (tid < 448) {
      int s  = tid / 14;
      int kk = tid - s * 14;
      int k  = kk * 2;
      const float* xs = xg + (size_t)(n0 + s) * 784 + t * 28 + k;
      float v0 = xs[0], v1 = xs[1];
      unsigned u = (unsigned)bf16r(v0) | ((unsigned)bf16r(v1) << 16);
      int mt = s >> 4;
      int addr = X_OFF + mt * 1024 + ((((k >> 3) & 3) << 4) + (s & 15)) * 16 + (k & 7) * 2;
      *(unsigned*)(smem + addr) = u;
    }
  };
  stage_x(0);
  __syncthreads();   // weights in LDS, x_0 staged, h zeroed

  const short8* Xf  = (const short8*)(smem + X_OFF);
  const short8* W1f = (const short8*)(smem + WIH1_OFF);
  const short8* H1f = (const short8*)(smem + H1_OFF);

  // per-lane constant part of the h-write address (A-frag tiled position of
  // element (s, d) with d = wave*16+mcol):
  const int kc_d   = wave >> 1;
  const int sub    = ((wave & 1) << 1) | (mcol >> 3);
  const int hconst = kc_d * 1024 + sub * 256 + q * 64 + (mcol & 7) * 2;

  int h0r = H0_OFF + 8192, h0w = H0_OFF;   // t=0: read zeros (buf1), write buf0

  float c0[2][4] = {{0.f,0.f,0.f,0.f},{0.f,0.f,0.f,0.f}};
  float c1[2][4] = {{0.f,0.f,0.f,0.f},{0.f,0.f,0.f,0.f}};

#pragma unroll 1
  for (int t = 0; t < 28; ++t) {
    float4_t acc[2][4];
    unsigned short hb[2][4];

    // ================= LAYER 0 : gates = b0 + x_t@Wih0^T + h0@Whh0^T =====
#pragma unroll
    for (int mt = 0; mt < 2; ++mt)
#pragma unroll
      for (int g = 0; g < 4; ++g)
        acc[mt][g] = (float4_t){bias0[g], bias0[g], bias0[g], bias0[g]};
#pragma unroll
    for (int mt = 0; mt < 2; ++mt) {
      short8 xf = Xf[mt * 64 + lane];
#pragma unroll
      for (int g = 0; g < 4; ++g)
        acc[mt][g] = __builtin_amdgcn_mfma_f32_16x16x32_bf16(xf, wih0[g], acc[mt][g], 0, 0, 0);
    }
    {
      const short8* H0R = (const short8*)(smem + h0r);
#pragma unroll
      for (int kc = 0; kc < 4; ++kc)
#pragma unroll
        for (int mt = 0; mt < 2; ++mt) {
          short8 hf = H0R[(mt * 4 + kc) * 64 + lane];
#pragma unroll
          for (int g = 0; g < 4; ++g)
            acc[mt][g] = __builtin_amdgcn_mfma_f32_16x16x32_bf16(hf, whh0[kc][g], acc[mt][g], 0, 0, 0);
        }
    }
    // activations (gate order i,f,g,o); c stays in registers.  h0_t written
    // DIRECTLY to buf[t&1]: that buffer's previous readers (L1(t-2), L0(t-1))
    // all completed before BarB(t-1) -> no pre-write barrier needed.
#pragma unroll
    for (int mt = 0; mt < 2; ++mt)
#pragma unroll
      for (int r = 0; r < 4; ++r) {
        float c = sigf(acc[mt][1][r]) * c0[mt][r] + sigf(acc[mt][0][r]) * tanhfast(acc[mt][2][r]);
        c0[mt][r] = c;
        *(unsigned short*)(smem + h0w + mt * 4096 + r * 16 + hconst) =
            bf16r(sigf(acc[mt][3][r]) * tanhfast(c));
      }

    __syncthreads();   // BarA: h0_t visible to all waves

    // ================= LAYER 1 : gates = b1 + h0_t@Wih1^T + h1@Whh1^T ====
#pragma unroll
    for (int mt = 0; mt < 2; ++mt)
#pragma unroll
      for (int g = 0; g < 4; ++g)
        acc[mt][g] = (float4_t){bias1[g], bias1[g], bias1[g], bias1[g]};
    {
      const short8* H0W = (const short8*)(smem + h0w);
#pragma unroll
      for (int kc = 0; kc < 4; ++kc) {
        short8 wf[4];
#pragma unroll
        for (int g = 0; g < 4; ++g)
          wf[g] = W1f[(kc * 32 + g * 8 + wave) * 64 + lane];
#pragma unroll
        for (int mt = 0; mt < 2; ++mt) {
          short8 hf = H0W[(mt * 4 + kc) * 64 + lane];
#pragma unroll
          for (int g = 0; g < 4; ++g)
            acc[mt][g] = __builtin_amdgcn_mfma_f32_16x16x32_bf16(hf, wf[g], acc[mt][g], 0, 0, 0);
        }
      }
#pragma unroll
      for (int kc = 0; kc < 4; ++kc)
#pragma unroll
        for (int mt = 0; mt < 2; ++mt) {
          short8 hf = H1f[(mt * 4 + kc) * 64 + lane];
#pragma unroll
          for (int g = 0; g < 4; ++g)
            acc[mt][g] = __builtin_amdgcn_mfma_f32_16x16x32_bf16(hf, whh1[kc][g], acc[mt][g], 0, 0, 0);
        }
    }
    // stage x_{t+1} (x_t reads finished in L0, before BarA; these writes
    // become visible to L0(t+1) after BarB)
    if (t < 27) stage_x(t + 1);
    // activations -> hb regs (h1 write must wait for BarB: single buffer)
#pragma unroll
    for (int mt = 0; mt < 2; ++mt)
#pragma unroll
      for (int r = 0; r < 4; ++r) {
        float c = sigf(acc[mt][1][r]) * c1[mt][r] + sigf(acc[mt][0][r]) * tanhfast(acc[mt][2][r]);
        c1[mt][r] = c;
        hb[mt][r] = bf16r(sigf(acc[mt][3][r]) * tanhfast(c));
      }

    __syncthreads();   // BarB: all h1_{t-1} reads done; x_{t+1} visible next

#pragma unroll
    for (int mt = 0; mt < 2; ++mt)
#pragma unroll
      for (int r = 0; r < 4; ++r)
        *(unsigned short*)(smem + H1_OFF + mt * 4096 + r * 16 + hconst) = hb[mt][r];

    h0r ^= 8192; h0w ^= 8192;
  }
  __syncthreads();     // final h1 visible for epilogue

  // ================= epilogue: out[s][o] = h1 . wout[o] + bout[o] =========
  if (tid < 320) {
    int s = tid / 10, o = tid - (tid / 10) * 10;
    float sum = bout[o];
#pragma unroll
    for (int kc = 0; kc < 4; ++kc)
#pragma unroll
      for (int sb = 0; sb < 4; ++sb) {
        short8 hv = H1f[((s >> 4) * 4 + kc) * 64 + sb * 16 + (s & 15)];
        int dbase = kc * 32 + sb * 8;
        float4_t w0 = *(const float4_t*)(wout + o * 128 + dbase);
        float4_t w1 = *(const float4_t*)(wout + o * 128 + dbase + 4);
#pragma unroll
        for (int j = 0; j < 4; ++j) {
          sum += bf2f((unsigned short)hv[j])     * w0[j];
          sum += bf2f((unsigned short)hv[j + 4]) * w1[j];
        }
      }
    out[(size_t)(n0 + s) * 10 + o] = sum;
  }
}

extern "C" void kernel_launch(void* const* d_in, const int* in_sizes, int n_in,
                              void* d_out, int out_size, void* d_ws, size_t ws_size,
                              hipStream_t stream) {
  const float* x    = (const float*)d_in[0];
  const float* wih0 = (const float*)d_in[1];
  const float* whh0 = (const float*)d_in[2];
  const float* bih0 = (const float*)d_in[3];
  const float* bhh0 = (const float*)d_in[4];
  const float* wih1 = (const float*)d_in[5];
  const float* whh1 = (const float*)d_in[6];
  const float* bih1 = (const float*)d_in[7];
  const float* bhh1 = (const float*)d_in[8];
  const float* wout = (const float*)d_in[9];
  const float* bout = (const float*)d_in[10];

  unsigned short* wp = (unsigned short*)d_ws;   // 425984 B used

  pack_weights<<<832, 256, 0, stream>>>(wih0, whh0, wih1, whh1, wp);
  lstm_fused<<<256, 512, 0, stream>>>(x, wp, bih0, bhh0, bih1, bhh1, wout, bout,
                                      (float*)d_out);
}

// Round 7
// 218.979 us; speedup vs baseline: 1.8059x; 1.2895x over previous
//
#include <hip/hip_runtime.h>

// ---------------------------------------------------------------------------
// Fused 2-layer LSTM, N=8192, T=28, I=28, H=128, + final [128->10] linear.
// One block = 32 samples through all 28 timesteps of both layers.
// grid = 256 blocks x 512 threads (8 waves) -> exactly 1 block / CU.
//
// R7 = R6 (passing, 227us/dispatch) + two changes driven by rocprof:
//   VALUBusy 67% / MfmaUtil 18.5% / HBM 1% -> VALU-issue-bound.
//   (1) sigf/tanhfast divides -> __builtin_amdgcn_rcpf (v_rcp_f32, 1 ULP).
//       At -O3 (no fast-math) each "1.0f/x" was the ~8-inst IEEE divide
//       sequence; 5 divides per LSTM cell x 16 cells/thread/t ~ 640
//       wasted VALU insts/thread/t (~half the VALU stream).
//   (2) stage_x(t+1) issued right after BarA (start of L1 phase) instead of
//       after the L1 MFMAs -> full L1 phase of global-load latency cover
//       before BarB's vmcnt drain.
//
// Structure (R6, verified): 2 barriers/timestep, h0 double-buffered in LDS
// (L0's h0_t write needs no pre-barrier: buf[t&1]'s previous readers --
// L1(t-2) and L0(t-1) -- completed before BarB(t-1)).  Schedule per t:
//     L0: read x_t + h0_{t-1}[(t-1)&1] -> MFMA -> acts -> write h0_t[t&1]
//     BarA: h0_t visible
//     L1: stage_x(t+1); read h0_t + h1_{t-1} -> MFMA -> acts -> hb
//     BarB: h1_{t-1} reads done; x_{t+1} visible for t+1
//     write h1_t (single buf; visible to L1(t+1) via BarA(t+1))
// LDS: wih1 131072 + h0 2x8192 + h1 8192 + x 2048 = 157696 <= 163840.
// ---------------------------------------------------------------------------

typedef short  short8   __attribute__((ext_vector_type(8)));
typedef float  float4_t __attribute__((ext_vector_type(4)));

#define WIH1_OFF 0        // 131072 B : w_ih1, persistent in LDS
#define H0_OFF   131072   // 2 x 8192 B : h0 double buffer
#define H1_OFF   147456   //     8192 B : h1 single buffer
#define X_OFF    155648   //     2048 B : x_t tile (k padded 28->32, zeros)
#define SMEM_SZ  157696

__device__ __forceinline__ unsigned short bf16r(float v) {
  union { float f; unsigned u; } x; x.f = v;
  unsigned r = x.u + 0x7fffu + ((x.u >> 16) & 1u);   // round-to-nearest-even
  return (unsigned short)(r >> 16);
}
__device__ __forceinline__ float bf2f(unsigned short b) {
  union { unsigned u; float f; } x; x.u = ((unsigned)b) << 16;
  return x.f;
}
// v_rcp_f32-based activations: 1-ULP rcp instead of the IEEE divide
// sequence (~8 insts).  Error ~1e-7 relative -- negligible vs bf16 quantum.
__device__ __forceinline__ float sigf(float x) {
  return __builtin_amdgcn_rcpf(1.0f + __expf(-x));
}
__device__ __forceinline__ float tanhfast(float x) {
  return 1.0f - 2.0f * __builtin_amdgcn_rcpf(__expf(2.0f * x) + 1.0f);
}

// ---------------------------------------------------------------------------
// Prologue: pack weights (fp32 -> bf16) into MFMA B-frag tiled layout in ws.
// ws (unsigned short units):
//   [0      ,16384) : w_ih0  [1 kc][32 tiles][64 lanes][8]  (k padded to 32)
//   [16384  ,81920) : w_hh0  [4 kc][32 tiles][64][8]
//   [81920 ,147456) : w_ih1  [4 kc][32][64][8]
//   [147456,212992) : w_hh1  [4 kc][32][64][8]
// element (tile,lane,j): row = tile*16 + (lane&15), k = kc*32 + (lane>>4)*8 + j
// ---------------------------------------------------------------------------
__global__ void pack_weights(const float* __restrict__ wih0, const float* __restrict__ whh0,
                             const float* __restrict__ wih1, const float* __restrict__ whh1,
                             unsigned short* __restrict__ dst)
{
  int e = blockIdx.x * 256 + threadIdx.x;
  const float* src; int K; int i;
  if      (e < 16384)  { src = wih0; K = 28;  i = e;          }
  else if (e < 81920)  { src = whh0; K = 128; i = e - 16384;  }
  else if (e < 147456) { src = wih1; K = 128; i = e - 81920;  }
  else if (e < 212992) { src = whh1; K = 128; i = e - 147456; }
  else return;
  int j = i & 7, lane = (i >> 3) & 63, tile = (i >> 9) & 31, kc = i >> 14;
  int row = tile * 16 + (lane & 15);
  int k = kc * 32 + ((lane >> 4) << 3) + j;
  float v = (k < K) ? src[row * K + k] : 0.0f;
  dst[e] = bf16r(v);
}

// ---------------------------------------------------------------------------
// Main fused kernel.
// ---------------------------------------------------------------------------
__global__ __launch_bounds__(512, 2)
void lstm_fused(const float* __restrict__ xg,
                const unsigned short* __restrict__ wpack,
                const float* __restrict__ bih0, const float* __restrict__ bhh0,
                const float* __restrict__ bih1, const float* __restrict__ bhh1,
                const float* __restrict__ wout, const float* __restrict__ bout,
                float* __restrict__ out)
{
  __shared__ __align__(16) char smem[SMEM_SZ];

  const int tid  = threadIdx.x;
  const int lane = tid & 63;
  const int wave = tid >> 6;          // 0..7, owns h-dims [wave*16, wave*16+16)
  const int q    = lane >> 4;         // quad: acc rows q*4 .. q*4+3
  const int mcol = lane & 15;         // acc col = h-dim within wave slice
  const int n0   = blockIdx.x * 32;   // batch tile base

  const short8* wp = (const short8*)wpack;

  // ---- persistent weight fragments in registers --------------------------
  short8 wih0[4], whh0[4][4], whh1[4][4];          // [g] / [kc][g]
#pragma unroll
  for (int g = 0; g < 4; ++g)
    wih0[g] = wp[(g * 8 + wave) * 64 + lane];
#pragma unroll
  for (int kc = 0; kc < 4; ++kc)
#pragma unroll
    for (int g = 0; g < 4; ++g) {
      whh0[kc][g] = wp[ 2048 + (kc * 32 + g * 8 + wave) * 64 + lane];
      whh1[kc][g] = wp[18432 + (kc * 32 + g * 8 + wave) * 64 + lane];
    }

  // ---- persistent w_ih1 in LDS (131072 B) --------------------------------
  {
    short8* dstp = (short8*)smem;
#pragma unroll
    for (int rr = 0; rr < 16; ++rr)
      dstp[rr * 512 + tid] = wp[10240 + rr * 512 + tid];
  }

  // ---- biases (per-lane, gate g, dim = wave*16+mcol) ---------------------
  float bias0[4], bias1[4];
  {
    const int d = wave * 16 + mcol;
#pragma unroll
    for (int g = 0; g < 4; ++g) {
      bias0[g] = bih0[g * 128 + d] + bhh0[g * 128 + d];
      bias1[g] = bih1[g * 128 + d] + bhh1[g * 128 + d];
    }
  }

  // ---- zero h0 read-buffer (B half), h1, and x pad region ---------------
  {
    int* z0 = (int*)(smem + H0_OFF + 8192);   // h0 buf1 (read as h0_{-1})
    int* z1 = (int*)(smem + H1_OFF);          // h1
#pragma unroll
    for (int rr = 0; rr < 4; ++rr) { z0[rr * 512 + tid] = 0; z1[rr * 512 + tid] = 0; }
    ((int*)(smem + X_OFF))[tid] = 0;          // x tile incl. k=28..31 pad
  }

  // ---- x_t staging: fp32 global -> bf16 A-frag tile in LDS ---------------
  auto stage_x = [&](int t) {
    if (tid < 448) {
      int s  = tid / 14;
      int kk = tid - s * 14;
      int k  = kk * 2;
      const float* xs = xg + (size_t)(n0 + s) * 784 + t * 28 + k;
      float v0 = xs[0], v1 = xs[1];
      unsigned u = (unsigned)bf16r(v0) | ((unsigned)bf16r(v1) << 16);
      int mt = s >> 4;
      int addr = X_OFF + mt * 1024 + ((((k >> 3) & 3) << 4) + (s & 15)) * 16 + (k & 7) * 2;
      *(unsigned*)(smem + addr) = u;
    }
  };
  stage_x(0);
  __syncthreads();   // weights in LDS, x_0 staged, h zeroed

  const short8* Xf  = (const short8*)(smem + X_OFF);
  const short8* W1f = (const short8*)(smem + WIH1_OFF);
  const short8* H1f = (const short8*)(smem + H1_OFF);

  // per-lane constant part of the h-write address (A-frag tiled position of
  // element (s, d) with d = wave*16+mcol):
  const int kc_d   = wave >> 1;
  const int sub    = ((wave & 1) << 1) | (mcol >> 3);
  const int hconst = kc_d * 1024 + sub * 256 + q * 64 + (mcol & 7) * 2;

  int h0r = H0_OFF + 8192, h0w = H0_OFF;   // t=0: read zeros (buf1), write buf0

  float c0[2][4] = {{0.f,0.f,0.f,0.f},{0.f,0.f,0.f,0.f}};
  float c1[2][4] = {{0.f,0.f,0.f,0.f},{0.f,0.f,0.f,0.f}};

#pragma unroll 1
  for (int t = 0; t < 28; ++t) {
    float4_t acc[2][4];
    unsigned short hb[2][4];

    // ================= LAYER 0 : gates = b0 + x_t@Wih0^T + h0@Whh0^T =====
#pragma unroll
    for (int mt = 0; mt < 2; ++mt)
#pragma unroll
      for (int g = 0; g < 4; ++g)
        acc[mt][g] = (float4_t){bias0[g], bias0[g], bias0[g], bias0[g]};
#pragma unroll
    for (int mt = 0; mt < 2; ++mt) {
      short8 xf = Xf[mt * 64 + lane];
#pragma unroll
      for (int g = 0; g < 4; ++g)
        acc[mt][g] = __builtin_amdgcn_mfma_f32_16x16x32_bf16(xf, wih0[g], acc[mt][g], 0, 0, 0);
    }
    {
      const short8* H0R = (const short8*)(smem + h0r);
#pragma unroll
      for (int kc = 0; kc < 4; ++kc)
#pragma unroll
        for (int mt = 0; mt < 2; ++mt) {
          short8 hf = H0R[(mt * 4 + kc) * 64 + lane];
#pragma unroll
          for (int g = 0; g < 4; ++g)
            acc[mt][g] = __builtin_amdgcn_mfma_f32_16x16x32_bf16(hf, whh0[kc][g], acc[mt][g], 0, 0, 0);
        }
    }
    // activations (gate order i,f,g,o); c stays in registers.  h0_t written
    // DIRECTLY to buf[t&1]: that buffer's previous readers (L1(t-2), L0(t-1))
    // all completed before BarB(t-1) -> no pre-write barrier needed.
#pragma unroll
    for (int mt = 0; mt < 2; ++mt)
#pragma unroll
      for (int r = 0; r < 4; ++r) {
        float c = sigf(acc[mt][1][r]) * c0[mt][r] + sigf(acc[mt][0][r]) * tanhfast(acc[mt][2][r]);
        c0[mt][r] = c;
        *(unsigned short*)(smem + h0w + mt * 4096 + r * 16 + hconst) =
            bf16r(sigf(acc[mt][3][r]) * tanhfast(c));
      }

    __syncthreads();   // BarA: h0_t visible to all waves

    // stage x_{t+1} EARLY: x_t reads finished in L0 (before BarA); issuing
    // the global loads here gives them the whole L1 phase of latency cover
    // before BarB's vmcnt drain.  Writes become visible to L0(t+1) at BarB.
    if (t < 27) stage_x(t + 1);

    // ================= LAYER 1 : gates = b1 + h0_t@Wih1^T + h1@Whh1^T ====
#pragma unroll
    for (int mt = 0; mt < 2; ++mt)
#pragma unroll
      for (int g = 0; g < 4; ++g)
        acc[mt][g] = (float4_t){bias1[g], bias1[g], bias1[g], bias1[g]};
    {
      const short8* H0W = (const short8*)(smem + h0w);
#pragma unroll
      for (int kc = 0; kc < 4; ++kc) {
        short8 wf[4];
#pragma unroll
        for (int g = 0; g < 4; ++g)
          wf[g] = W1f[(kc * 32 + g * 8 + wave) * 64 + lane];
#pragma unroll
        for (int mt = 0; mt < 2; ++mt) {
          short8 hf = H0W[(mt * 4 + kc) * 64 + lane];
#pragma unroll
          for (int g = 0; g < 4; ++g)
            acc[mt][g] = __builtin_amdgcn_mfma_f32_16x16x32_bf16(hf, wf[g], acc[mt][g], 0, 0, 0);
        }
      }
#pragma unroll
      for (int kc = 0; kc < 4; ++kc)
#pragma unroll
        for (int mt = 0; mt < 2; ++mt) {
          short8 hf = H1f[(mt * 4 + kc) * 64 + lane];
#pragma unroll
          for (int g = 0; g < 4; ++g)
            acc[mt][g] = __builtin_amdgcn_mfma_f32_16x16x32_bf16(hf, whh1[kc][g], acc[mt][g], 0, 0, 0);
        }
    }
    // activations -> hb regs (h1 write must wait for BarB: single buffer)
#pragma unroll
    for (int mt = 0; mt < 2; ++mt)
#pragma unroll
      for (int r = 0; r < 4; ++r) {
        float c = sigf(acc[mt][1][r]) * c1[mt][r] + sigf(acc[mt][0][r]) * tanhfast(acc[mt][2][r]);
        c1[mt][r] = c;
        hb[mt][r] = bf16r(sigf(acc[mt][3][r]) * tanhfast(c));
      }

    __syncthreads();   // BarB: all h1_{t-1} reads done; x_{t+1} visible next

#pragma unroll
    for (int mt = 0; mt < 2; ++mt)
#pragma unroll
      for (int r = 0; r < 4; ++r)
        *(unsigned short*)(smem + H1_OFF + mt * 4096 + r * 16 + hconst) = hb[mt][r];

    h0r ^= 8192; h0w ^= 8192;
  }
  __syncthreads();     // final h1 visible for epilogue

  // ================= epilogue: out[s][o] = h1 . wout[o] + bout[o] =========
  if (tid < 320) {
    int s = tid / 10, o = tid - (tid / 10) * 10;
    float sum = bout[o];
#pragma unroll
    for (int kc = 0; kc < 4; ++kc)
#pragma unroll
      for (int sb = 0; sb < 4; ++sb) {
        short8 hv = H1f[((s >> 4) * 4 + kc) * 64 + sb * 16 + (s & 15)];
        int dbase = kc * 32 + sb * 8;
        float4_t w0 = *(const float4_t*)(wout + o * 128 + dbase);
        float4_t w1 = *(const float4_t*)(wout + o * 128 + dbase + 4);
#pragma unroll
        for (int j = 0; j < 4; ++j) {
          sum += bf2f((unsigned short)hv[j])     * w0[j];
          sum += bf2f((unsigned short)hv[j + 4]) * w1[j];
        }
      }
    out[(size_t)(n0 + s) * 10 + o] = sum;
  }
}

extern "C" void kernel_launch(void* const* d_in, const int* in_sizes, int n_in,
                              void* d_out, int out_size, void* d_ws, size_t ws_size,
                              hipStream_t stream) {
  const float* x    = (const float*)d_in[0];
  const float* wih0 = (const float*)d_in[1];
  const float* whh0 = (const float*)d_in[2];
  const float* bih0 = (const float*)d_in[3];
  const float* bhh0 = (const float*)d_in[4];
  const float* wih1 = (const float*)d_in[5];
  const float* whh1 = (const float*)d_in[6];
  const float* bih1 = (const float*)d_in[7];
  const float* bhh1 = (const float*)d_in[8];
  const float* wout = (const float*)d_in[9];
  const float* bout = (const float*)d_in[10];

  unsigned short* wp = (unsigned short*)d_ws;   // 425984 B used

  pack_weights<<<832, 256, 0, stream>>>(wih0, whh0, wih1, whh1, wp);
  lstm_fused<<<256, 512, 0, stream>>>(x, wp, bih0, bhh0, bih1, bhh1, wout, bout,
                                      (float*)d_out);
}